// Round 6
// baseline (297.802 us; speedup 1.0000x reference)
//
#include <hip/hip_runtime.h>
#include <hip/hip_bf16.h>

#define NNODES 100000
#define HID 256
#define NMOVES 500000
#define NGRAPHS 512
#define BM 64
#define PB 128   // partial-reduction blocks

typedef __attribute__((ext_vector_type(8))) short short8;
typedef __attribute__((ext_vector_type(4))) float f32x4;

#define AS_GLOBAL __attribute__((address_space(1)))
#define AS_LDS __attribute__((address_space(3)))

__device__ __forceinline__ unsigned f2bf(float f) {
    unsigned u = __builtin_bit_cast(unsigned, f);
    u += 0x7FFFu + ((u >> 16) & 1u);   // round-to-nearest-even
    return u >> 16;
}
__device__ __forceinline__ float bf2f(ushort h) {
    unsigned u = ((unsigned)h) << 16;
    return __builtin_bit_cast(float, u);
}
// order-preserving float<->uint encoding for max
__device__ __forceinline__ unsigned encf(float f) {
    unsigned b = __builtin_bit_cast(unsigned, f);
    return (b & 0x80000000u) ? ~b : (b ^ 0x80000000u);
}
__device__ __forceinline__ float decf(unsigned u) {
    unsigned b = (u & 0x80000000u) ? (u ^ 0x80000000u) : ~u;
    return __builtin_bit_cast(float, b);
}

// ---- build W1' transposed: W1t[n][k] ----
__global__ void k_convert_w1(const float* __restrict__ W1, ushort* __restrict__ W1t) {
    int t = blockIdx.x * blockDim.x + threadIdx.x; // 131072
    int n = t >> 8, k = t & 255;
    float v = (n < 256) ? W1[k * 256 + n] : W1[(k + 256) * 256 + (n - 256)];
    W1t[t] = (ushort)f2bf(v);
}

// ---- barrier-free GEMM: P[m][n] = sum_k emb[m][k] * W1t[n][k] ----
// A panel (64x256) staged once in LDS (f32->bf16, XOR swizzle), ONE barrier,
// A fragments then live in 64 VGPRs for the whole kernel. B fragments are
// loaded straight from global (256KB total -> L2-resident). 4 N-strips x
// (16 B-loads -> 32 MFMA -> packed stores), zero barriers after the first.
__global__ __launch_bounds__(512, 2) void k_gemm(const float* __restrict__ emb,
                                                 const ushort* __restrict__ Bt,
                                                 ushort* __restrict__ P, int M) {
    __shared__ __align__(16) ushort Asm[BM * 256];      // 32 KB
    int tid = threadIdx.x;
    int lane = tid & 63;
    int wave = tid >> 6;
    int tm = blockIdx.x * BM;
    int wm = wave >> 2;   // 0..1 (32-row group)
    int wn = wave & 3;    // 0..3 (32-col group within strip)
    int fr = lane & 15;
    int q = lane >> 4;

    // ---- stage A panel: convert f32->bf16 in-register, swizzled ds_write ----
#pragma unroll
    for (int it = 0; it < 4; ++it) {
        int c = it * 512 + tid;          // 16B chunk id 0..2047
        int row = c >> 5;                // 0..63
        int j = c & 31;
        int grow = tm + row;
        if (grow >= M) grow = M - 1;
        const float4* sp = reinterpret_cast<const float4*>(emb + (size_t)grow * 256 + j * 8);
        float4 v0 = sp[0], v1 = sp[1];
        uint4 o;
        o.x = f2bf(v0.x) | (f2bf(v0.y) << 16);
        o.y = f2bf(v0.z) | (f2bf(v0.w) << 16);
        o.z = f2bf(v1.x) | (f2bf(v1.y) << 16);
        o.w = f2bf(v1.z) | (f2bf(v1.w) << 16);
        int dst = row * 512 + ((j ^ (row & 7)) << 4);
        *reinterpret_cast<uint4*>(reinterpret_cast<char*>(Asm) + dst) = o;
    }
    __syncthreads();   // the only barrier

    // ---- load A fragments into registers: afr[m][kt], held all kernel ----
    const char* Ab = reinterpret_cast<const char*>(Asm);
    short8 afr[2][8];
#pragma unroll
    for (int m = 0; m < 2; ++m) {
        int row = wm * 32 + m * 16 + fr;
#pragma unroll
        for (int kt = 0; kt < 8; ++kt) {
            int abyte = row * 512 + (((kt * 4 + q) ^ (fr & 7)) << 4);
            afr[m][kt] = *reinterpret_cast<const short8*>(Ab + abyte);
        }
    }

    // ---- 4 N-strips: B frags from global (L2), 32 MFMA, packed stores ----
#pragma unroll 1
    for (int r = 0; r < 4; ++r) {
        int rowb = r * 128 + wn * 32;
        short8 bfv[2][8];
#pragma unroll
        for (int n = 0; n < 2; ++n) {
            const ushort* bp = Bt + (size_t)(rowb + n * 16 + fr) * 256 + q * 8;
#pragma unroll
            for (int kt = 0; kt < 8; ++kt)
                bfv[n][kt] = *reinterpret_cast<const short8*>(bp + kt * 32);
        }

        f32x4 acc[2][2];
#pragma unroll
        for (int n = 0; n < 2; ++n)
#pragma unroll
            for (int m = 0; m < 2; ++m) acc[n][m] = (f32x4){0.f, 0.f, 0.f, 0.f};

#pragma unroll
        for (int kt = 0; kt < 8; ++kt)
#pragma unroll
            for (int n = 0; n < 2; ++n)
#pragma unroll
                for (int m = 0; m < 2; ++m)
                    acc[n][m] = __builtin_amdgcn_mfma_f32_16x16x32_bf16(bfv[n][kt], afr[m][kt], acc[n][m], 0, 0, 0);

#pragma unroll
        for (int m = 0; m < 2; ++m) {
            int prow = tm + wm * 32 + m * 16 + fr;
            if (prow < M) {
#pragma unroll
                for (int n = 0; n < 2; ++n) {
                    int pcol = rowb + n * 16 + q * 4;
                    uint2 pk;
                    pk.x = f2bf(acc[n][m][0]) | (f2bf(acc[n][m][1]) << 16);
                    pk.y = f2bf(acc[n][m][2]) | (f2bf(acc[n][m][3]) << 16);
                    *reinterpret_cast<uint2*>(P + (size_t)prow * 512 + pcol) = pk;
                }
            }
        }
    }
}

// ---- per-move MLP tail: 16 lanes/move, 4 moves/wave, unroll x2. NO atomics ----
__device__ __forceinline__ float dot8(uint4 a, uint4 b, const float* b1v, const float* w2v, int o) {
    unsigned aw[4] = {a.x, a.y, a.z, a.w};
    unsigned bw[4] = {b.x, b.y, b.z, b.w};
    float r = 0.f;
#pragma unroll
    for (int i = 0; i < 4; ++i) {
        float a0 = bf2f((ushort)(aw[i] & 0xffffu));
        float a1 = bf2f((ushort)(aw[i] >> 16));
        float c0 = bf2f((ushort)(bw[i] & 0xffffu));
        float c1 = bf2f((ushort)(bw[i] >> 16));
        float h0 = fmaxf(a0 + c0 + b1v[o + 2 * i], 0.f);
        float h1 = fmaxf(a1 + c1 + b1v[o + 2 * i + 1], 0.f);
        r += h0 * w2v[o + 2 * i] + h1 * w2v[o + 2 * i + 1];
    }
    return r;
}

__global__ __launch_bounds__(256) void k_moves(const int* __restrict__ srcs,
                                               const int* __restrict__ tgts,
                                               const int* __restrict__ batch,
                                               const ushort* __restrict__ P,
                                               const float* __restrict__ b1,
                                               const float* __restrict__ W2,
                                               const float* __restrict__ b2,
                                               float* __restrict__ logits,
                                               int* __restrict__ mb) {
    int tid = threadIdx.x;
    int lane = tid & 63;
    int sub = lane >> 4;
    int ch = lane & 15;

    float b1v[16], w2v[16];
    const float4* b1p = reinterpret_cast<const float4*>(b1);
    const float4* w2p = reinterpret_cast<const float4*>(W2);
#pragma unroll
    for (int q = 0; q < 4; ++q) {
        float4 bv = b1p[ch * 4 + q];
        float4 wv = w2p[ch * 4 + q];
        b1v[q * 4 + 0] = bv.x; b1v[q * 4 + 1] = bv.y; b1v[q * 4 + 2] = bv.z; b1v[q * 4 + 3] = bv.w;
        w2v[q * 4 + 0] = wv.x; w2v[q * 4 + 1] = wv.y; w2v[q * 4 + 2] = wv.z; w2v[q * 4 + 3] = wv.w;
    }
    float b2s = b2[0];

    int wid = (blockIdx.x * 256 + tid) >> 6;
    int nw = (gridDim.x * 256) >> 6;

    for (int base = wid * 8; base < NMOVES; base += nw * 8) {
        int m0 = base + sub;
        int m1 = base + 4 + sub;
        int s0 = srcs[m0], t0 = tgts[m0];
        int s1 = srcs[m1], t1 = tgts[m1];
        const uint4* pa0 = reinterpret_cast<const uint4*>(P + (size_t)s0 * 512 + ch * 16);
        const uint4* pb0 = reinterpret_cast<const uint4*>(P + (size_t)t0 * 512 + 256 + ch * 16);
        const uint4* pa1 = reinterpret_cast<const uint4*>(P + (size_t)s1 * 512 + ch * 16);
        const uint4* pb1 = reinterpret_cast<const uint4*>(P + (size_t)t1 * 512 + 256 + ch * 16);
        uint4 a00 = pa0[0], a01 = pa0[1];
        uint4 c00 = pb0[0], c01 = pb0[1];
        uint4 a10 = pa1[0], a11 = pa1[1];
        uint4 c10 = pb1[0], c11 = pb1[1];
        int g0 = batch[s0];
        int g1 = batch[s1];

        float p0 = dot8(a00, c00, b1v, w2v, 0) + dot8(a01, c01, b1v, w2v, 8);
        float p1 = dot8(a10, c10, b1v, w2v, 0) + dot8(a11, c11, b1v, w2v, 8);
#pragma unroll
        for (int off = 1; off < 16; off <<= 1) {
            p0 += __shfl_xor(p0, off);
            p1 += __shfl_xor(p1, off);
        }
        if (ch == 0) {
            logits[m0] = p0 + b2s; mb[m0] = g0;
            logits[m1] = p1 + b2s; mb[m1] = g1;
        }
    }
}

// ---- per-block segment partials: LDS max + LDS sum, non-atomic global flush ----
__global__ __launch_bounds__(256) void k_part(const float* __restrict__ logits,
                                              const int* __restrict__ mb,
                                              float* __restrict__ pmax,
                                              float* __restrict__ psum) {
    __shared__ unsigned lmax[NGRAPHS];
    __shared__ float lsum[NGRAPHS];
    int tid = threadIdx.x;
    lmax[tid] = 0u; lmax[tid + 256] = 0u;
    lsum[tid] = 0.f; lsum[tid + 256] = 0.f;
    __syncthreads();

    int stride = PB * 256;
    for (int m = blockIdx.x * 256 + tid; m < NMOVES; m += stride)
        atomicMax(&lmax[mb[m]], encf(logits[m]));
    __syncthreads();
    for (int m = blockIdx.x * 256 + tid; m < NMOVES; m += stride) {
        int g = mb[m];
        atomicAdd(&lsum[g], __expf(logits[m] - decf(lmax[g])));
    }
    __syncthreads();

#pragma unroll
    for (int i = 0; i < 2; ++i) {
        int s = tid + i * 256;
        unsigned e = lmax[s];
        pmax[blockIdx.x * NGRAPHS + s] = (e == 0u) ? -INFINITY : decf(e);
        psum[blockIdx.x * NGRAPHS + s] = lsum[s];
    }
}

// ---- fold PB partials per segment -> global max, 1/(sum+eps) ----
__global__ void k_combine(const float* __restrict__ pmax, const float* __restrict__ psum,
                          float* __restrict__ gmax, float* __restrict__ ginv) {
    int s = threadIdx.x; // 512
    float M = -INFINITY;
#pragma unroll 4
    for (int b = 0; b < PB; ++b) M = fmaxf(M, pmax[b * NGRAPHS + s]);
    float S = 0.f;
#pragma unroll 4
    for (int b = 0; b < PB; ++b) {
        float pm = pmax[b * NGRAPHS + s];
        float ps = psum[b * NGRAPHS + s];
        if (ps > 0.f) S += ps * __expf(pm - M);
    }
    gmax[s] = M;
    ginv[s] = 1.f / (S + 1e-16f);
}

__global__ void k_norm(const float* __restrict__ logits, const int* __restrict__ mb,
                       const float* __restrict__ gmax, const float* __restrict__ ginv,
                       float* __restrict__ out) {
    int i = blockIdx.x * blockDim.x + threadIdx.x;
    int n = gridDim.x * blockDim.x;
    for (int m = i; m < NMOVES; m += n) {
        int g = mb[m];
        out[m] = __expf(logits[m] - gmax[g]) * ginv[g];
    }
}

extern "C" void kernel_launch(void* const* d_in, const int* in_sizes, int n_in,
                              void* d_out, int out_size, void* d_ws, size_t ws_size,
                              hipStream_t stream) {
    const float* emb = (const float*)d_in[0];
    const int* moves = (const int*)d_in[1];
    const int* batch = (const int*)d_in[2];
    const float* W1 = (const float*)d_in[3];
    const float* b1 = (const float*)d_in[4];
    const float* W2 = (const float*)d_in[5];
    const float* b2 = (const float*)d_in[6];
    float* out = (float*)d_out;

    auto al = [](size_t x) { return (x + 255) & ~(size_t)255; };
    char* ws = (char*)d_ws;
    size_t off = 0;
    ushort* W1t = (ushort*)(ws + off); off += al((size_t)512 * 256 * 2);
    ushort* P   = (ushort*)(ws + off); off += al((size_t)NNODES * 512 * 2);
    float* logits = (float*)(ws + off); off += al((size_t)NMOVES * 4);
    int* mb       = (int*)(ws + off);   off += al((size_t)NMOVES * 4);
    float* pmax   = (float*)(ws + off); off += al((size_t)PB * NGRAPHS * 4);
    float* psum   = (float*)(ws + off); off += al((size_t)PB * NGRAPHS * 4);
    float* gmax   = (float*)(ws + off); off += al((size_t)NGRAPHS * 4);
    float* ginv   = (float*)(ws + off); off += al((size_t)NGRAPHS * 4);

    k_convert_w1<<<512, 256, 0, stream>>>(W1, W1t);

    int tiles_m = (NNODES + BM - 1) / BM;   // 1563
    k_gemm<<<tiles_m, 512, 0, stream>>>(emb, W1t, P, NNODES);

    k_moves<<<2048, 256, 0, stream>>>(moves, moves + NMOVES, batch, P, b1, W2, b2,
                                      logits, mb);
    k_part<<<PB, 256, 0, stream>>>(logits, mb, pmax, psum);
    k_combine<<<1, NGRAPHS, 0, stream>>>(pmax, psum, gmax, ginv);
    k_norm<<<1024, 256, 0, stream>>>(logits, mb, gmax, ginv, out);
}

// Round 7
// 232.685 us; speedup vs baseline: 1.2799x; 1.2799x over previous
//
#include <hip/hip_runtime.h>
#include <hip/hip_bf16.h>

#define NNODES 100000
#define HID 256
#define NMOVES 500000
#define NGRAPHS 512
#define BM 64
#define BN 64
#define PB 128   // partial-reduction blocks

typedef __attribute__((ext_vector_type(8))) short short8;
typedef __attribute__((ext_vector_type(4))) float f32x4;

#define AS_GLOBAL __attribute__((address_space(1)))
#define AS_LDS __attribute__((address_space(3)))

__device__ __forceinline__ unsigned f2bf(float f) {
    unsigned u = __builtin_bit_cast(unsigned, f);
    u += 0x7FFFu + ((u >> 16) & 1u);   // round-to-nearest-even
    return u >> 16;
}
__device__ __forceinline__ float bf2f(ushort h) {
    unsigned u = ((unsigned)h) << 16;
    return __builtin_bit_cast(float, u);
}
// order-preserving float<->uint encoding for max
__device__ __forceinline__ unsigned encf(float f) {
    unsigned b = __builtin_bit_cast(unsigned, f);
    return (b & 0x80000000u) ? ~b : (b ^ 0x80000000u);
}
__device__ __forceinline__ float decf(unsigned u) {
    unsigned b = (u & 0x80000000u) ? (u ^ 0x80000000u) : ~u;
    return __builtin_bit_cast(float, b);
}

// ---- build W1' transposed: W1t[n][k] ----
__global__ void k_convert_w1(const float* __restrict__ W1, ushort* __restrict__ W1t) {
    int t = blockIdx.x * blockDim.x + threadIdx.x; // 131072
    int n = t >> 8, k = t & 255;
    float v = (n < 256) ? W1[k * 256 + n] : W1[(k + 256) * 256 + (n - 256)];
    W1t[t] = (ushort)f2bf(v);
}

// ---- GEMM: P[m][n] = sum_k emb[m][k] * W1t[n][k] ----
// Phase 1: stage A panel (64x256, f32->bf16, XOR swizzle) in lds[0:32K).
// Phase 2: extract A fragments to 64 VGPRs (statically indexed).
// Phase 3: LDS overlay becomes a double-buffered B pipeline: 8 strips of
// BN=64 P-cols x full K (32KB each), staged via global_load_lds w=16 with
// pre-swizzled source; stage of strip r+1 flies under MFMA of strip r.
// 16 MFMA per barrier per wave. Swapped MFMA -> packed 8B epilogue stores.
__global__ __launch_bounds__(512, 4) void k_gemm(const float* __restrict__ emb,
                                                 const ushort* __restrict__ Bt,
                                                 ushort* __restrict__ P, int M) {
    __shared__ __align__(16) char lds[65536];
    int tid = threadIdx.x;
    int lane = tid & 63;
    int wave = tid >> 6;
    int tm = blockIdx.x * BM;
    int wm = wave >> 2;   // 0..1 (32-row group)
    int wn = wave & 3;    // 0..3 (16-col group within strip)
    int fr = lane & 15;
    int q = lane >> 4;
    int sw = fr & 7;

    // ---- Phase 1: stage A (f32->bf16, swizzled ds_write) ----
#pragma unroll
    for (int i = 0; i < 4; ++i) {
        int cid = i * 512 + tid;         // 16B chunk id, 0..2047
        int row = cid >> 5;              // 0..63
        int j = cid & 31;
        int grow = tm + row; if (grow >= M) grow = M - 1;
        const float4* sp = reinterpret_cast<const float4*>(emb + (size_t)grow * 256 + (j << 3));
        float4 v0 = sp[0], v1 = sp[1];
        uint4 o;
        o.x = f2bf(v0.x) | (f2bf(v0.y) << 16);
        o.y = f2bf(v0.z) | (f2bf(v0.w) << 16);
        o.z = f2bf(v1.x) | (f2bf(v1.y) << 16);
        o.w = f2bf(v1.z) | (f2bf(v1.w) << 16);
        *reinterpret_cast<uint4*>(lds + row * 512 + ((j ^ (row & 7)) << 4)) = o;
    }
    __syncthreads();

    // ---- Phase 2: A fragments -> registers (16 x short8 = 64 VGPR) ----
    short8 af[2][8];
#pragma unroll
    for (int m = 0; m < 2; ++m) {
        int row = wm * 32 + m * 16 + fr;
#pragma unroll
        for (int kt = 0; kt < 8; ++kt)
            af[m][kt] = *reinterpret_cast<const short8*>(
                lds + row * 512 + (((kt * 4 + q) ^ sw) << 4));
    }
    __syncthreads();   // all waves extracted; lds region now free for B

    // ---- Phase 3: B strips, double-buffered ----
    // prologue: stage strip 0 into buf 0
#pragma unroll
    for (int i = 0; i < 4; ++i) {
        int cid = i * 512 + tid;
        int row = cid >> 5, c = cid & 31;
        const ushort* src = Bt + (size_t)row * 256 + ((c ^ (row & 7)) << 3);
        __builtin_amdgcn_global_load_lds((const AS_GLOBAL void*)src,
            (AS_LDS void*)(lds + (i * 512 + wave * 64) * 16), 16, 0, 0);
    }

#pragma unroll 1
    for (int r = 0; r < 8; ++r) {
        __syncthreads();                 // stage(r) drained; buf(r-1) readers done
        int bufb = (r & 1) << 15;
        if (r < 7) {                     // stage strip r+1 into other buffer
            int tn2 = (r + 1) * BN;
            int buf2 = ((r + 1) & 1) << 15;
#pragma unroll
            for (int i = 0; i < 4; ++i) {
                int cid = i * 512 + tid;
                int row = cid >> 5, c = cid & 31;
                const ushort* src = Bt + (size_t)(tn2 + row) * 256 + ((c ^ (row & 7)) << 3);
                __builtin_amdgcn_global_load_lds((const AS_GLOBAL void*)src,
                    (AS_LDS void*)(lds + buf2 + (i * 512 + wave * 64) * 16), 16, 0, 0);
            }
        }
        const char* bp = lds + bufb + (wn * 16 + fr) * 512;
        f32x4 acc0 = {0.f, 0.f, 0.f, 0.f};
        f32x4 acc1 = {0.f, 0.f, 0.f, 0.f};
#pragma unroll
        for (int kt = 0; kt < 8; ++kt) {
            short8 bf = *reinterpret_cast<const short8*>(bp + (((kt * 4 + q) ^ sw) << 4));
            acc0 = __builtin_amdgcn_mfma_f32_16x16x32_bf16(bf, af[0][kt], acc0, 0, 0, 0);
            acc1 = __builtin_amdgcn_mfma_f32_16x16x32_bf16(bf, af[1][kt], acc1, 0, 0, 0);
        }
        // epilogue: this strip's 16 cols, rows wm*32 + {0,16} + fr
        int pcol = r * BN + wn * 16 + q * 4;
        int prow0 = tm + wm * 32 + fr;
        if (prow0 < M) {
            uint2 pk;
            pk.x = f2bf(acc0[0]) | (f2bf(acc0[1]) << 16);
            pk.y = f2bf(acc0[2]) | (f2bf(acc0[3]) << 16);
            *reinterpret_cast<uint2*>(P + (size_t)prow0 * 512 + pcol) = pk;
        }
        int prow1 = prow0 + 16;
        if (prow1 < M) {
            uint2 pk;
            pk.x = f2bf(acc1[0]) | (f2bf(acc1[1]) << 16);
            pk.y = f2bf(acc1[2]) | (f2bf(acc1[3]) << 16);
            *reinterpret_cast<uint2*>(P + (size_t)prow1 * 512 + pcol) = pk;
        }
    }
}

// ---- per-move MLP tail: 16 lanes/move, 4 moves/wave, unroll x2. NO atomics ----
__device__ __forceinline__ float dot8(uint4 a, uint4 b, const float* b1v, const float* w2v, int o) {
    unsigned aw[4] = {a.x, a.y, a.z, a.w};
    unsigned bw[4] = {b.x, b.y, b.z, b.w};
    float r = 0.f;
#pragma unroll
    for (int i = 0; i < 4; ++i) {
        float a0 = bf2f((ushort)(aw[i] & 0xffffu));
        float a1 = bf2f((ushort)(aw[i] >> 16));
        float c0 = bf2f((ushort)(bw[i] & 0xffffu));
        float c1 = bf2f((ushort)(bw[i] >> 16));
        float h0 = fmaxf(a0 + c0 + b1v[o + 2 * i], 0.f);
        float h1 = fmaxf(a1 + c1 + b1v[o + 2 * i + 1], 0.f);
        r += h0 * w2v[o + 2 * i] + h1 * w2v[o + 2 * i + 1];
    }
    return r;
}

__global__ __launch_bounds__(256) void k_moves(const int* __restrict__ srcs,
                                               const int* __restrict__ tgts,
                                               const int* __restrict__ batch,
                                               const ushort* __restrict__ P,
                                               const float* __restrict__ b1,
                                               const float* __restrict__ W2,
                                               const float* __restrict__ b2,
                                               float* __restrict__ logits,
                                               int* __restrict__ mb) {
    int tid = threadIdx.x;
    int lane = tid & 63;
    int sub = lane >> 4;
    int ch = lane & 15;

    float b1v[16], w2v[16];
    const float4* b1p = reinterpret_cast<const float4*>(b1);
    const float4* w2p = reinterpret_cast<const float4*>(W2);
#pragma unroll
    for (int q = 0; q < 4; ++q) {
        float4 bv = b1p[ch * 4 + q];
        float4 wv = w2p[ch * 4 + q];
        b1v[q * 4 + 0] = bv.x; b1v[q * 4 + 1] = bv.y; b1v[q * 4 + 2] = bv.z; b1v[q * 4 + 3] = bv.w;
        w2v[q * 4 + 0] = wv.x; w2v[q * 4 + 1] = wv.y; w2v[q * 4 + 2] = wv.z; w2v[q * 4 + 3] = wv.w;
    }
    float b2s = b2[0];

    int wid = (blockIdx.x * 256 + tid) >> 6;
    int nw = (gridDim.x * 256) >> 6;

    for (int base = wid * 8; base < NMOVES; base += nw * 8) {
        int m0 = base + sub;
        int m1 = base + 4 + sub;
        int s0 = srcs[m0], t0 = tgts[m0];
        int s1 = srcs[m1], t1 = tgts[m1];
        const uint4* pa0 = reinterpret_cast<const uint4*>(P + (size_t)s0 * 512 + ch * 16);
        const uint4* pb0 = reinterpret_cast<const uint4*>(P + (size_t)t0 * 512 + 256 + ch * 16);
        const uint4* pa1 = reinterpret_cast<const uint4*>(P + (size_t)s1 * 512 + ch * 16);
        const uint4* pb1 = reinterpret_cast<const uint4*>(P + (size_t)t1 * 512 + 256 + ch * 16);
        uint4 a00 = pa0[0], a01 = pa0[1];
        uint4 c00 = pb0[0], c01 = pb0[1];
        uint4 a10 = pa1[0], a11 = pa1[1];
        uint4 c10 = pb1[0], c11 = pb1[1];
        int g0 = batch[s0];
        int g1 = batch[s1];

        float p0 = dot8(a00, c00, b1v, w2v, 0) + dot8(a01, c01, b1v, w2v, 8);
        float p1 = dot8(a10, c10, b1v, w2v, 0) + dot8(a11, c11, b1v, w2v, 8);
#pragma unroll
        for (int off = 1; off < 16; off <<= 1) {
            p0 += __shfl_xor(p0, off);
            p1 += __shfl_xor(p1, off);
        }
        if (ch == 0) {
            logits[m0] = p0 + b2s; mb[m0] = g0;
            logits[m1] = p1 + b2s; mb[m1] = g1;
        }
    }
}

// ---- per-block segment partials (vectorized 4 moves/thread) ----
__global__ __launch_bounds__(256) void k_part(const float* __restrict__ logits,
                                              const int* __restrict__ mb,
                                              float* __restrict__ pmax,
                                              float* __restrict__ psum) {
    __shared__ unsigned lmax[NGRAPHS];
    __shared__ float lsum[NGRAPHS];
    int tid = threadIdx.x;
    lmax[tid] = 0u; lmax[tid + 256] = 0u;
    lsum[tid] = 0.f; lsum[tid + 256] = 0.f;
    __syncthreads();

    const int NV = NMOVES / 4;
    int stride = PB * 256;
    for (int v = blockIdx.x * 256 + tid; v < NV; v += stride) {
        float4 l = reinterpret_cast<const float4*>(logits)[v];
        int4 g = reinterpret_cast<const int4*>(mb)[v];
        atomicMax(&lmax[g.x], encf(l.x));
        atomicMax(&lmax[g.y], encf(l.y));
        atomicMax(&lmax[g.z], encf(l.z));
        atomicMax(&lmax[g.w], encf(l.w));
    }
    __syncthreads();
    for (int v = blockIdx.x * 256 + tid; v < NV; v += stride) {
        float4 l = reinterpret_cast<const float4*>(logits)[v];
        int4 g = reinterpret_cast<const int4*>(mb)[v];
        atomicAdd(&lsum[g.x], __expf(l.x - decf(lmax[g.x])));
        atomicAdd(&lsum[g.y], __expf(l.y - decf(lmax[g.y])));
        atomicAdd(&lsum[g.z], __expf(l.z - decf(lmax[g.z])));
        atomicAdd(&lsum[g.w], __expf(l.w - decf(lmax[g.w])));
    }
    __syncthreads();

#pragma unroll
    for (int i = 0; i < 2; ++i) {
        int s = tid + i * 256;
        unsigned e = lmax[s];
        pmax[blockIdx.x * NGRAPHS + s] = (e == 0u) ? -INFINITY : decf(e);
        psum[blockIdx.x * NGRAPHS + s] = lsum[s];
    }
}

// ---- fold PB partials per segment -> global max, 1/(sum+eps) ----
__global__ void k_combine(const float* __restrict__ pmax, const float* __restrict__ psum,
                          float* __restrict__ gmax, float* __restrict__ ginv) {
    int s = threadIdx.x; // 512
    float M = -INFINITY;
#pragma unroll 4
    for (int b = 0; b < PB; ++b) M = fmaxf(M, pmax[b * NGRAPHS + s]);
    float S = 0.f;
#pragma unroll 4
    for (int b = 0; b < PB; ++b) {
        float pm = pmax[b * NGRAPHS + s];
        float ps = psum[b * NGRAPHS + s];
        if (ps > 0.f) S += ps * __expf(pm - M);
    }
    gmax[s] = M;
    ginv[s] = 1.f / (S + 1e-16f);
}

// ---- normalize (vectorized 4 moves/thread) ----
__global__ void k_norm(const float* __restrict__ logits, const int* __restrict__ mb,
                       const float* __restrict__ gmax, const float* __restrict__ ginv,
                       float* __restrict__ out) {
    const int NV = NMOVES / 4;
    int i = blockIdx.x * blockDim.x + threadIdx.x;
    int n = gridDim.x * blockDim.x;
    for (int v = i; v < NV; v += n) {
        float4 l = reinterpret_cast<const float4*>(logits)[v];
        int4 g = reinterpret_cast<const int4*>(mb)[v];
        float4 o;
        o.x = __expf(l.x - gmax[g.x]) * ginv[g.x];
        o.y = __expf(l.y - gmax[g.y]) * ginv[g.y];
        o.z = __expf(l.z - gmax[g.z]) * ginv[g.z];
        o.w = __expf(l.w - gmax[g.w]) * ginv[g.w];
        reinterpret_cast<float4*>(out)[v] = o;
    }
}

extern "C" void kernel_launch(void* const* d_in, const int* in_sizes, int n_in,
                              void* d_out, int out_size, void* d_ws, size_t ws_size,
                              hipStream_t stream) {
    const float* emb = (const float*)d_in[0];
    const int* moves = (const int*)d_in[1];
    const int* batch = (const int*)d_in[2];
    const float* W1 = (const float*)d_in[3];
    const float* b1 = (const float*)d_in[4];
    const float* W2 = (const float*)d_in[5];
    const float* b2 = (const float*)d_in[6];
    float* out = (float*)d_out;

    auto al = [](size_t x) { return (x + 255) & ~(size_t)255; };
    char* ws = (char*)d_ws;
    size_t off = 0;
    ushort* W1t = (ushort*)(ws + off); off += al((size_t)512 * 256 * 2);
    ushort* P   = (ushort*)(ws + off); off += al((size_t)NNODES * 512 * 2);
    float* logits = (float*)(ws + off); off += al((size_t)NMOVES * 4);
    int* mb       = (int*)(ws + off);   off += al((size_t)NMOVES * 4);
    float* pmax   = (float*)(ws + off); off += al((size_t)PB * NGRAPHS * 4);
    float* psum   = (float*)(ws + off); off += al((size_t)PB * NGRAPHS * 4);
    float* gmax   = (float*)(ws + off); off += al((size_t)NGRAPHS * 4);
    float* ginv   = (float*)(ws + off); off += al((size_t)NGRAPHS * 4);

    k_convert_w1<<<512, 256, 0, stream>>>(W1, W1t);

    int tiles_m = (NNODES + BM - 1) / BM;   // 1563
    k_gemm<<<tiles_m, 512, 0, stream>>>(emb, W1t, P, NNODES);

    k_moves<<<2048, 256, 0, stream>>>(moves, moves + NMOVES, batch, P, b1, W2, b2,
                                      logits, mb);
    k_part<<<PB, 256, 0, stream>>>(logits, mb, pmax, psum);
    k_combine<<<1, NGRAPHS, 0, stream>>>(pmax, psum, gmax, ginv);
    k_norm<<<512, 256, 0, stream>>>(logits, mb, gmax, ginv, out);
}

// Round 8
// 222.468 us; speedup vs baseline: 1.3386x; 1.0459x over previous
//
#include <hip/hip_runtime.h>
#include <hip/hip_bf16.h>

#define NNODES 100000
#define HID 256
#define NMOVES 500000
#define NGRAPHS 512
#define BM 128
#define BN 32
#define PB 128   // partial-reduction blocks

typedef __attribute__((ext_vector_type(8))) short short8;
typedef __attribute__((ext_vector_type(4))) float f32x4;

#define AS_GLOBAL __attribute__((address_space(1)))
#define AS_LDS __attribute__((address_space(3)))

__device__ __forceinline__ unsigned f2bf(float f) {
    unsigned u = __builtin_bit_cast(unsigned, f);
    u += 0x7FFFu + ((u >> 16) & 1u);   // round-to-nearest-even
    return u >> 16;
}
__device__ __forceinline__ float bf2f(ushort h) {
    unsigned u = ((unsigned)h) << 16;
    return __builtin_bit_cast(float, u);
}
// order-preserving float<->uint encoding for max
__device__ __forceinline__ unsigned encf(float f) {
    unsigned b = __builtin_bit_cast(unsigned, f);
    return (b & 0x80000000u) ? ~b : (b ^ 0x80000000u);
}
__device__ __forceinline__ float decf(unsigned u) {
    unsigned b = (u & 0x80000000u) ? (u ^ 0x80000000u) : ~u;
    return __builtin_bit_cast(float, b);
}

// ---- build W1' transposed: W1t[n][k] ----
__global__ void k_convert_w1(const float* __restrict__ W1, ushort* __restrict__ W1t) {
    int t = blockIdx.x * blockDim.x + threadIdx.x; // 131072
    int n = t >> 8, k = t & 255;
    float v = (n < 256) ? W1[k * 256 + n] : W1[(k + 256) * 256 + (n - 256)];
    W1t[t] = (ushort)f2bf(v);
}

// ---- GEMM: P[m][n] = sum_k emb[m][k] * W1t[n][k] ----
// BM=128 A panel staged once (f32->bf16, XOR swizzle) -> af[2][8] in AGPRs ->
// LDS overlaid by double-buffered BN=32 B strips. Counted-vmcnt raw-barrier
// pipeline: stages + stores stay in flight across barriers (no vmcnt(0) drain
// in the loop). R0-orientation epilogue: lane = P-col -> 32B coalesced stores.
__global__ __launch_bounds__(512, 4) void k_gemm(const float* __restrict__ emb,
                                                 const ushort* __restrict__ Bt,
                                                 ushort* __restrict__ P, int M) {
    __shared__ __align__(16) char lds[65536];
    int tid = threadIdx.x;
    int lane = tid & 63;
    int wave = tid >> 6;
    int tm = blockIdx.x * BM;
    int wm = wave >> 1;   // 0..3  (32-row group)
    int wn = wave & 1;    // 0..1  (16-col group within strip)
    int fr = lane & 15;
    int q = lane >> 4;    // 0..3
    int sw = fr & 7;

    // ---- Phase 1: stage A 128x256 (f32->bf16, swizzled ds_write) ----
#pragma unroll
    for (int i = 0; i < 8; ++i) {
        int cid = i * 512 + tid;         // 16B-bf16 chunk id, 0..4095
        int row = cid >> 5;              // 0..127
        int j = cid & 31;
        int grow = tm + row; if (grow >= M) grow = M - 1;
        const float4* sp = reinterpret_cast<const float4*>(emb + (size_t)grow * 256 + (j << 3));
        float4 v0 = sp[0], v1 = sp[1];
        uint4 o;
        o.x = f2bf(v0.x) | (f2bf(v0.y) << 16);
        o.y = f2bf(v0.z) | (f2bf(v0.w) << 16);
        o.z = f2bf(v1.x) | (f2bf(v1.y) << 16);
        o.w = f2bf(v1.z) | (f2bf(v1.w) << 16);
        *reinterpret_cast<uint4*>(lds + row * 512 + ((j ^ (row & 7)) << 4)) = o;
    }
    __syncthreads();

    // ---- Phase 2: A fragments -> AGPRs (16 x short8) ----
    short8 af[2][8];
#pragma unroll
    for (int m = 0; m < 2; ++m) {
        int row = wm * 32 + m * 16 + fr;
#pragma unroll
        for (int kt = 0; kt < 8; ++kt)
            af[m][kt] = *reinterpret_cast<const short8*>(
                lds + row * 512 + (((kt * 4 + q) ^ sw) << 4));
    }
    __syncthreads();   // all waves extracted; lds region now free for B

    // ---- Phase 3: 16 B strips (BN=32), double-buffered, counted vmcnt ----
    // stage = 2 gload_lds per thread; strip buffer 16KB at buf*16384.
#define STAGE(STRIP, BUFI)                                                          \
    {                                                                               \
        int tn2 = (STRIP) * BN;                                                     \
        _Pragma("unroll")                                                           \
        for (int i = 0; i < 2; ++i) {                                               \
            int cid = i * 512 + tid;                                                \
            int row = cid >> 5, c = cid & 31;                                       \
            const ushort* src = Bt + (size_t)(tn2 + row) * 256 + ((c ^ (row & 7)) << 3); \
            __builtin_amdgcn_global_load_lds((const AS_GLOBAL void*)src,            \
                (AS_LDS void*)(lds + (BUFI) * 16384 + (i * 512 + wave * 64) * 16),  \
                16, 0, 0);                                                          \
        }                                                                           \
    }

    STAGE(0, 0);
    STAGE(1, 1);

#pragma unroll 1
    for (int r = 0; r < 16; ++r) {
        // wait for stage(r) only (FIFO: loads+stores count in issue order)
        if (r == 0)      asm volatile("s_waitcnt vmcnt(2)" ::: "memory");
        else if (r < 15) asm volatile("s_waitcnt vmcnt(10)" ::: "memory");
        else             asm volatile("s_waitcnt vmcnt(8)" ::: "memory");
        asm volatile("s_barrier" ::: "memory");

        const char* bp = lds + (r & 1) * 16384;
        f32x4 acc0 = {0.f, 0.f, 0.f, 0.f};
        f32x4 acc1 = {0.f, 0.f, 0.f, 0.f};
#pragma unroll
        for (int kt = 0; kt < 8; ++kt) {
            short8 bf = *reinterpret_cast<const short8*>(
                bp + (wn * 16 + fr) * 512 + (((kt * 4 + q) ^ sw) << 4));
            acc0 = __builtin_amdgcn_mfma_f32_16x16x32_bf16(af[0][kt], bf, acc0, 0, 0, 0);
            acc1 = __builtin_amdgcn_mfma_f32_16x16x32_bf16(af[1][kt], bf, acc1, 0, 0, 0);
        }
        // epilogue: lane = P-col (fr), rows q*4+j; 8 ushort stores, 32B sectors
        int pcol = r * BN + wn * 16 + fr;
#pragma unroll
        for (int j = 0; j < 4; ++j) {
            int prow0 = tm + wm * 32 + q * 4 + j;
            if (prow0 < M) P[(size_t)prow0 * 512 + pcol] = (ushort)f2bf(acc0[j]);
            int prow1 = prow0 + 16;
            if (prow1 < M) P[(size_t)prow1 * 512 + pcol] = (ushort)f2bf(acc1[j]);
        }

        asm volatile("s_barrier" ::: "memory");   // all waves done reading buf
        if (r < 14) STAGE(r + 2, (r & 1));
    }
#undef STAGE
}

// ---- per-move MLP tail: 16 lanes/move, 4 moves/wave, unroll x2. NO atomics ----
__device__ __forceinline__ float dot8(uint4 a, uint4 b, const float* b1v, const float* w2v, int o) {
    unsigned aw[4] = {a.x, a.y, a.z, a.w};
    unsigned bw[4] = {b.x, b.y, b.z, b.w};
    float r = 0.f;
#pragma unroll
    for (int i = 0; i < 4; ++i) {
        float a0 = bf2f((ushort)(aw[i] & 0xffffu));
        float a1 = bf2f((ushort)(aw[i] >> 16));
        float c0 = bf2f((ushort)(bw[i] & 0xffffu));
        float c1 = bf2f((ushort)(bw[i] >> 16));
        float h0 = fmaxf(a0 + c0 + b1v[o + 2 * i], 0.f);
        float h1 = fmaxf(a1 + c1 + b1v[o + 2 * i + 1], 0.f);
        r += h0 * w2v[o + 2 * i] + h1 * w2v[o + 2 * i + 1];
    }
    return r;
}

__global__ __launch_bounds__(256) void k_moves(const int* __restrict__ srcs,
                                               const int* __restrict__ tgts,
                                               const int* __restrict__ batch,
                                               const ushort* __restrict__ P,
                                               const float* __restrict__ b1,
                                               const float* __restrict__ W2,
                                               const float* __restrict__ b2,
                                               float* __restrict__ logits,
                                               int* __restrict__ mb) {
    int tid = threadIdx.x;
    int lane = tid & 63;
    int sub = lane >> 4;
    int ch = lane & 15;

    float b1v[16], w2v[16];
    const float4* b1p = reinterpret_cast<const float4*>(b1);
    const float4* w2p = reinterpret_cast<const float4*>(W2);
#pragma unroll
    for (int q = 0; q < 4; ++q) {
        float4 bv = b1p[ch * 4 + q];
        float4 wv = w2p[ch * 4 + q];
        b1v[q * 4 + 0] = bv.x; b1v[q * 4 + 1] = bv.y; b1v[q * 4 + 2] = bv.z; b1v[q * 4 + 3] = bv.w;
        w2v[q * 4 + 0] = wv.x; w2v[q * 4 + 1] = wv.y; w2v[q * 4 + 2] = wv.z; w2v[q * 4 + 3] = wv.w;
    }
    float b2s = b2[0];

    int wid = (blockIdx.x * 256 + tid) >> 6;
    int nw = (gridDim.x * 256) >> 6;

    for (int base = wid * 8; base < NMOVES; base += nw * 8) {
        int m0 = base + sub;
        int m1 = base + 4 + sub;
        int s0 = srcs[m0], t0 = tgts[m0];
        int s1 = srcs[m1], t1 = tgts[m1];
        const uint4* pa0 = reinterpret_cast<const uint4*>(P + (size_t)s0 * 512 + ch * 16);
        const uint4* pb0 = reinterpret_cast<const uint4*>(P + (size_t)t0 * 512 + 256 + ch * 16);
        const uint4* pa1 = reinterpret_cast<const uint4*>(P + (size_t)s1 * 512 + ch * 16);
        const uint4* pb1 = reinterpret_cast<const uint4*>(P + (size_t)t1 * 512 + 256 + ch * 16);
        uint4 a00 = pa0[0], a01 = pa0[1];
        uint4 c00 = pb0[0], c01 = pb0[1];
        uint4 a10 = pa1[0], a11 = pa1[1];
        uint4 c10 = pb1[0], c11 = pb1[1];
        int g0 = batch[s0];
        int g1 = batch[s1];

        float p0 = dot8(a00, c00, b1v, w2v, 0) + dot8(a01, c01, b1v, w2v, 8);
        float p1 = dot8(a10, c10, b1v, w2v, 0) + dot8(a11, c11, b1v, w2v, 8);
#pragma unroll
        for (int off = 1; off < 16; off <<= 1) {
            p0 += __shfl_xor(p0, off);
            p1 += __shfl_xor(p1, off);
        }
        if (ch == 0) {
            logits[m0] = p0 + b2s; mb[m0] = g0;
            logits[m1] = p1 + b2s; mb[m1] = g1;
        }
    }
}

// ---- per-block segment partials (vectorized 4 moves/thread) ----
__global__ __launch_bounds__(256) void k_part(const float* __restrict__ logits,
                                              const int* __restrict__ mb,
                                              float* __restrict__ pmax,
                                              float* __restrict__ psum) {
    __shared__ unsigned lmax[NGRAPHS];
    __shared__ float lsum[NGRAPHS];
    int tid = threadIdx.x;
    lmax[tid] = 0u; lmax[tid + 256] = 0u;
    lsum[tid] = 0.f; lsum[tid + 256] = 0.f;
    __syncthreads();

    const int NV = NMOVES / 4;
    int stride = PB * 256;
    for (int v = blockIdx.x * 256 + tid; v < NV; v += stride) {
        float4 l = reinterpret_cast<const float4*>(logits)[v];
        int4 g = reinterpret_cast<const int4*>(mb)[v];
        atomicMax(&lmax[g.x], encf(l.x));
        atomicMax(&lmax[g.y], encf(l.y));
        atomicMax(&lmax[g.z], encf(l.z));
        atomicMax(&lmax[g.w], encf(l.w));
    }
    __syncthreads();
    for (int v = blockIdx.x * 256 + tid; v < NV; v += stride) {
        float4 l = reinterpret_cast<const float4*>(logits)[v];
        int4 g = reinterpret_cast<const int4*>(mb)[v];
        atomicAdd(&lsum[g.x], __expf(l.x - decf(lmax[g.x])));
        atomicAdd(&lsum[g.y], __expf(l.y - decf(lmax[g.y])));
        atomicAdd(&lsum[g.z], __expf(l.z - decf(lmax[g.z])));
        atomicAdd(&lsum[g.w], __expf(l.w - decf(lmax[g.w])));
    }
    __syncthreads();

#pragma unroll
    for (int i = 0; i < 2; ++i) {
        int s = tid + i * 256;
        unsigned e = lmax[s];
        pmax[blockIdx.x * NGRAPHS + s] = (e == 0u) ? -INFINITY : decf(e);
        psum[blockIdx.x * NGRAPHS + s] = lsum[s];
    }
}

// ---- fold PB partials per segment -> global max, 1/(sum+eps) ----
__global__ void k_combine(const float* __restrict__ pmax, const float* __restrict__ psum,
                          float* __restrict__ gmax, float* __restrict__ ginv) {
    int s = threadIdx.x; // 512
    float M = -INFINITY;
#pragma unroll 4
    for (int b = 0; b < PB; ++b) M = fmaxf(M, pmax[b * NGRAPHS + s]);
    float S = 0.f;
#pragma unroll 4
    for (int b = 0; b < PB; ++b) {
        float pm = pmax[b * NGRAPHS + s];
        float ps = psum[b * NGRAPHS + s];
        if (ps > 0.f) S += ps * __expf(pm - M);
    }
    gmax[s] = M;
    ginv[s] = 1.f / (S + 1e-16f);
}

// ---- normalize (vectorized 4 moves/thread) ----
__global__ void k_norm(const float* __restrict__ logits, const int* __restrict__ mb,
                       const float* __restrict__ gmax, const float* __restrict__ ginv,
                       float* __restrict__ out) {
    const int NV = NMOVES / 4;
    int i = blockIdx.x * blockDim.x + threadIdx.x;
    int n = gridDim.x * blockDim.x;
    for (int v = i; v < NV; v += n) {
        float4 l = reinterpret_cast<const float4*>(logits)[v];
        int4 g = reinterpret_cast<const int4*>(mb)[v];
        float4 o;
        o.x = __expf(l.x - gmax[g.x]) * ginv[g.x];
        o.y = __expf(l.y - gmax[g.y]) * ginv[g.y];
        o.z = __expf(l.z - gmax[g.z]) * ginv[g.z];
        o.w = __expf(l.w - gmax[g.w]) * ginv[g.w];
        reinterpret_cast<float4*>(out)[v] = o;
    }
}

extern "C" void kernel_launch(void* const* d_in, const int* in_sizes, int n_in,
                              void* d_out, int out_size, void* d_ws, size_t ws_size,
                              hipStream_t stream) {
    const float* emb = (const float*)d_in[0];
    const int* moves = (const int*)d_in[1];
    const int* batch = (const int*)d_in[2];
    const float* W1 = (const float*)d_in[3];
    const float* b1 = (const float*)d_in[4];
    const float* W2 = (const float*)d_in[5];
    const float* b2 = (const float*)d_in[6];
    float* out = (float*)d_out;

    auto al = [](size_t x) { return (x + 255) & ~(size_t)255; };
    char* ws = (char*)d_ws;
    size_t off = 0;
    ushort* W1t = (ushort*)(ws + off); off += al((size_t)512 * 256 * 2);
    ushort* P   = (ushort*)(ws + off); off += al((size_t)NNODES * 512 * 2);
    float* logits = (float*)(ws + off); off += al((size_t)NMOVES * 4);
    int* mb       = (int*)(ws + off);   off += al((size_t)NMOVES * 4);
    float* pmax   = (float*)(ws + off); off += al((size_t)PB * NGRAPHS * 4);
    float* psum   = (float*)(ws + off); off += al((size_t)PB * NGRAPHS * 4);
    float* gmax   = (float*)(ws + off); off += al((size_t)NGRAPHS * 4);
    float* ginv   = (float*)(ws + off); off += al((size_t)NGRAPHS * 4);

    k_convert_w1<<<512, 256, 0, stream>>>(W1, W1t);

    int tiles_m = (NNODES + BM - 1) / BM;   // 782
    k_gemm<<<tiles_m, 512, 0, stream>>>(emb, W1t, P, NNODES);

    k_moves<<<2048, 256, 0, stream>>>(moves, moves + NMOVES, batch, P, b1, W2, b2,
                                      logits, mb);
    k_part<<<PB, 256, 0, stream>>>(logits, mb, pmax, psum);
    k_combine<<<1, NGRAPHS, 0, stream>>>(pmax, psum, gmax, ginv);
    k_norm<<<512, 256, 0, stream>>>(logits, mb, gmax, ginv, out);
}

// Round 9
// 146.862 us; speedup vs baseline: 2.0278x; 1.5148x over previous
//
#include <hip/hip_runtime.h>
#include <hip/hip_bf16.h>

#define NNODES 100000
#define HID 256
#define NMOVES 500000
#define NGRAPHS 512
#define BM 128
#define BN 32
#define PB 128   // partial-reduction blocks

typedef __attribute__((ext_vector_type(8))) short short8;
typedef __attribute__((ext_vector_type(4))) float f32x4;

#define AS_GLOBAL __attribute__((address_space(1)))
#define AS_LDS __attribute__((address_space(3)))

__device__ __forceinline__ unsigned f2bf(float f) {
    unsigned u = __builtin_bit_cast(unsigned, f);
    u += 0x7FFFu + ((u >> 16) & 1u);   // round-to-nearest-even
    return u >> 16;
}
__device__ __forceinline__ float bf2f(ushort h) {
    unsigned u = ((unsigned)h) << 16;
    return __builtin_bit_cast(float, u);
}
// order-preserving float<->uint encoding for max
__device__ __forceinline__ unsigned encf(float f) {
    unsigned b = __builtin_bit_cast(unsigned, f);
    return (b & 0x80000000u) ? ~b : (b ^ 0x80000000u);
}
__device__ __forceinline__ float decf(unsigned u) {
    unsigned b = (u & 0x80000000u) ? (u ^ 0x80000000u) : ~u;
    return __builtin_bit_cast(float, b);
}

// ---- build W1' transposed: W1t[n][k] ----
__global__ void k_convert_w1(const float* __restrict__ W1, ushort* __restrict__ W1t) {
    int t = blockIdx.x * blockDim.x + threadIdx.x; // 131072
    int n = t >> 8, k = t & 255;
    float v = (n < 256) ? W1[k * 256 + n] : W1[(k + 256) * 256 + (n - 256)];
    W1t[t] = (ushort)f2bf(v);
}

// ---- GEMM: P[m][n] = sum_k emb[m][k] * W1t[n][k] ---- (unchanged from R8)
__global__ __launch_bounds__(512, 4) void k_gemm(const float* __restrict__ emb,
                                                 const ushort* __restrict__ Bt,
                                                 ushort* __restrict__ P, int M) {
    __shared__ __align__(16) char lds[65536];
    int tid = threadIdx.x;
    int lane = tid & 63;
    int wave = tid >> 6;
    int tm = blockIdx.x * BM;
    int wm = wave >> 1;   // 0..3  (32-row group)
    int wn = wave & 1;    // 0..1  (16-col group within strip)
    int fr = lane & 15;
    int q = lane >> 4;    // 0..3
    int sw = fr & 7;

    // ---- Phase 1: stage A 128x256 (f32->bf16, swizzled ds_write) ----
#pragma unroll
    for (int i = 0; i < 8; ++i) {
        int cid = i * 512 + tid;         // 16B-bf16 chunk id, 0..4095
        int row = cid >> 5;              // 0..127
        int j = cid & 31;
        int grow = tm + row; if (grow >= M) grow = M - 1;
        const float4* sp = reinterpret_cast<const float4*>(emb + (size_t)grow * 256 + (j << 3));
        float4 v0 = sp[0], v1 = sp[1];
        uint4 o;
        o.x = f2bf(v0.x) | (f2bf(v0.y) << 16);
        o.y = f2bf(v0.z) | (f2bf(v0.w) << 16);
        o.z = f2bf(v1.x) | (f2bf(v1.y) << 16);
        o.w = f2bf(v1.z) | (f2bf(v1.w) << 16);
        *reinterpret_cast<uint4*>(lds + row * 512 + ((j ^ (row & 7)) << 4)) = o;
    }
    __syncthreads();

    // ---- Phase 2: A fragments -> registers (16 x short8) ----
    short8 af[2][8];
#pragma unroll
    for (int m = 0; m < 2; ++m) {
        int row = wm * 32 + m * 16 + fr;
#pragma unroll
        for (int kt = 0; kt < 8; ++kt)
            af[m][kt] = *reinterpret_cast<const short8*>(
                lds + row * 512 + (((kt * 4 + q) ^ sw) << 4));
    }
    __syncthreads();   // all waves extracted; lds region now free for B

    // ---- Phase 3: 16 B strips (BN=32), double-buffered, counted vmcnt ----
#define STAGE(STRIP, BUFI)                                                          \
    {                                                                               \
        int tn2 = (STRIP) * BN;                                                     \
        _Pragma("unroll")                                                           \
        for (int i = 0; i < 2; ++i) {                                               \
            int cid = i * 512 + tid;                                                \
            int row = cid >> 5, c = cid & 31;                                       \
            const ushort* src = Bt + (size_t)(tn2 + row) * 256 + ((c ^ (row & 7)) << 3); \
            __builtin_amdgcn_global_load_lds((const AS_GLOBAL void*)src,            \
                (AS_LDS void*)(lds + (BUFI) * 16384 + (i * 512 + wave * 64) * 16),  \
                16, 0, 0);                                                          \
        }                                                                           \
    }

    STAGE(0, 0);
    STAGE(1, 1);

#pragma unroll 1
    for (int r = 0; r < 16; ++r) {
        if (r == 0)      asm volatile("s_waitcnt vmcnt(2)" ::: "memory");
        else if (r < 15) asm volatile("s_waitcnt vmcnt(10)" ::: "memory");
        else             asm volatile("s_waitcnt vmcnt(8)" ::: "memory");
        asm volatile("s_barrier" ::: "memory");

        const char* bp = lds + (r & 1) * 16384;
        f32x4 acc0 = {0.f, 0.f, 0.f, 0.f};
        f32x4 acc1 = {0.f, 0.f, 0.f, 0.f};
#pragma unroll
        for (int kt = 0; kt < 8; ++kt) {
            short8 bf = *reinterpret_cast<const short8*>(
                bp + (wn * 16 + fr) * 512 + (((kt * 4 + q) ^ sw) << 4));
            acc0 = __builtin_amdgcn_mfma_f32_16x16x32_bf16(af[0][kt], bf, acc0, 0, 0, 0);
            acc1 = __builtin_amdgcn_mfma_f32_16x16x32_bf16(af[1][kt], bf, acc1, 0, 0, 0);
        }
        int pcol = r * BN + wn * 16 + fr;
#pragma unroll
        for (int j = 0; j < 4; ++j) {
            int prow0 = tm + wm * 32 + q * 4 + j;
            if (prow0 < M) P[(size_t)prow0 * 512 + pcol] = (ushort)f2bf(acc0[j]);
            int prow1 = prow0 + 16;
            if (prow1 < M) P[(size_t)prow1 * 512 + pcol] = (ushort)f2bf(acc1[j]);
        }

        asm volatile("s_barrier" ::: "memory");
        if (r < 14) STAGE(r + 2, (r & 1));
    }
#undef STAGE
}

// ---- per-move MLP tail: 16 lanes/move, 4 moves/wave, unroll x2. NO atomics ----
__device__ __forceinline__ float dot8(uint4 a, uint4 b, const float* b1v, const float* w2v, int o) {
    unsigned aw[4] = {a.x, a.y, a.z, a.w};
    unsigned bw[4] = {b.x, b.y, b.z, b.w};
    float r = 0.f;
#pragma unroll
    for (int i = 0; i < 4; ++i) {
        float a0 = bf2f((ushort)(aw[i] & 0xffffu));
        float a1 = bf2f((ushort)(aw[i] >> 16));
        float c0 = bf2f((ushort)(bw[i] & 0xffffu));
        float c1 = bf2f((ushort)(bw[i] >> 16));
        float h0 = fmaxf(a0 + c0 + b1v[o + 2 * i], 0.f);
        float h1 = fmaxf(a1 + c1 + b1v[o + 2 * i + 1], 0.f);
        r += h0 * w2v[o + 2 * i] + h1 * w2v[o + 2 * i + 1];
    }
    return r;
}

__global__ __launch_bounds__(256) void k_moves(const int* __restrict__ srcs,
                                               const int* __restrict__ tgts,
                                               const int* __restrict__ batch,
                                               const ushort* __restrict__ P,
                                               const float* __restrict__ b1,
                                               const float* __restrict__ W2,
                                               const float* __restrict__ b2,
                                               float* __restrict__ logits,
                                               int* __restrict__ mb) {
    int tid = threadIdx.x;
    int lane = tid & 63;
    int sub = lane >> 4;
    int ch = lane & 15;

    float b1v[16], w2v[16];
    const float4* b1p = reinterpret_cast<const float4*>(b1);
    const float4* w2p = reinterpret_cast<const float4*>(W2);
#pragma unroll
    for (int q = 0; q < 4; ++q) {
        float4 bv = b1p[ch * 4 + q];
        float4 wv = w2p[ch * 4 + q];
        b1v[q * 4 + 0] = bv.x; b1v[q * 4 + 1] = bv.y; b1v[q * 4 + 2] = bv.z; b1v[q * 4 + 3] = bv.w;
        w2v[q * 4 + 0] = wv.x; w2v[q * 4 + 1] = wv.y; w2v[q * 4 + 2] = wv.z; w2v[q * 4 + 3] = wv.w;
    }
    float b2s = b2[0];

    int wid = (blockIdx.x * 256 + tid) >> 6;
    int nw = (gridDim.x * 256) >> 6;

    for (int base = wid * 8; base < NMOVES; base += nw * 8) {
        int m0 = base + sub;
        int m1 = base + 4 + sub;
        int s0 = srcs[m0], t0 = tgts[m0];
        int s1 = srcs[m1], t1 = tgts[m1];
        const uint4* pa0 = reinterpret_cast<const uint4*>(P + (size_t)s0 * 512 + ch * 16);
        const uint4* pb0 = reinterpret_cast<const uint4*>(P + (size_t)t0 * 512 + 256 + ch * 16);
        const uint4* pa1 = reinterpret_cast<const uint4*>(P + (size_t)s1 * 512 + ch * 16);
        const uint4* pb1 = reinterpret_cast<const uint4*>(P + (size_t)t1 * 512 + 256 + ch * 16);
        uint4 a00 = pa0[0], a01 = pa0[1];
        uint4 c00 = pb0[0], c01 = pb0[1];
        uint4 a10 = pa1[0], a11 = pa1[1];
        uint4 c10 = pb1[0], c11 = pb1[1];
        int g0 = batch[s0];
        int g1 = batch[s1];

        float p0 = dot8(a00, c00, b1v, w2v, 0) + dot8(a01, c01, b1v, w2v, 8);
        float p1 = dot8(a10, c10, b1v, w2v, 0) + dot8(a11, c11, b1v, w2v, 8);
#pragma unroll
        for (int off = 1; off < 16; off <<= 1) {
            p0 += __shfl_xor(p0, off);
            p1 += __shfl_xor(p1, off);
        }
        if (ch == 0) {
            logits[m0] = p0 + b2s; mb[m0] = g0;
            logits[m1] = p1 + b2s; mb[m1] = g1;
        }
    }
}

// ---- per-block segment partials (vectorized 4 moves/thread) ----
__global__ __launch_bounds__(256) void k_part(const float* __restrict__ logits,
                                              const int* __restrict__ mb,
                                              float* __restrict__ pmax,
                                              float* __restrict__ psum) {
    __shared__ unsigned lmax[NGRAPHS];
    __shared__ float lsum[NGRAPHS];
    int tid = threadIdx.x;
    lmax[tid] = 0u; lmax[tid + 256] = 0u;
    lsum[tid] = 0.f; lsum[tid + 256] = 0.f;
    __syncthreads();

    const int NV = NMOVES / 4;
    int stride = PB * 256;
    for (int v = blockIdx.x * 256 + tid; v < NV; v += stride) {
        float4 l = reinterpret_cast<const float4*>(logits)[v];
        int4 g = reinterpret_cast<const int4*>(mb)[v];
        atomicMax(&lmax[g.x], encf(l.x));
        atomicMax(&lmax[g.y], encf(l.y));
        atomicMax(&lmax[g.z], encf(l.z));
        atomicMax(&lmax[g.w], encf(l.w));
    }
    __syncthreads();
    for (int v = blockIdx.x * 256 + tid; v < NV; v += stride) {
        float4 l = reinterpret_cast<const float4*>(logits)[v];
        int4 g = reinterpret_cast<const int4*>(mb)[v];
        atomicAdd(&lsum[g.x], __expf(l.x - decf(lmax[g.x])));
        atomicAdd(&lsum[g.y], __expf(l.y - decf(lmax[g.y])));
        atomicAdd(&lsum[g.z], __expf(l.z - decf(lmax[g.z])));
        atomicAdd(&lsum[g.w], __expf(l.w - decf(lmax[g.w])));
    }
    __syncthreads();

#pragma unroll
    for (int i = 0; i < 2; ++i) {
        int s = tid + i * 256;
        unsigned e = lmax[s];
        pmax[blockIdx.x * NGRAPHS + s] = (e == 0u) ? -INFINITY : decf(e);
        psum[blockIdx.x * NGRAPHS + s] = lsum[s];
    }
}

// ---- fold PB partials per segment: one block per segment, wave-parallel ----
__global__ __launch_bounds__(64) void k_combine(const float* __restrict__ pmax,
                                                const float* __restrict__ psum,
                                                float* __restrict__ gmax,
                                                float* __restrict__ ginv) {
    int s = blockIdx.x;      // segment 0..511
    int lane = threadIdx.x;  // 0..63
    float pm0 = pmax[lane * NGRAPHS + s];
    float pm1 = pmax[(lane + 64) * NGRAPHS + s];
    float ps0 = psum[lane * NGRAPHS + s];
    float ps1 = psum[(lane + 64) * NGRAPHS + s];
    float M = fmaxf(pm0, pm1);
#pragma unroll
    for (int off = 32; off; off >>= 1) M = fmaxf(M, __shfl_xor(M, off));
    float S = (ps0 > 0.f ? ps0 * __expf(pm0 - M) : 0.f)
            + (ps1 > 0.f ? ps1 * __expf(pm1 - M) : 0.f);
#pragma unroll
    for (int off = 32; off; off >>= 1) S += __shfl_xor(S, off);
    if (lane == 0) {
        gmax[s] = M;
        ginv[s] = 1.f / (S + 1e-16f);
    }
}

// ---- normalize (vectorized 4 moves/thread) ----
__global__ void k_norm(const float* __restrict__ logits, const int* __restrict__ mb,
                       const float* __restrict__ gmax, const float* __restrict__ ginv,
                       float* __restrict__ out) {
    const int NV = NMOVES / 4;
    int i = blockIdx.x * blockDim.x + threadIdx.x;
    int n = gridDim.x * blockDim.x;
    for (int v = i; v < NV; v += n) {
        float4 l = reinterpret_cast<const float4*>(logits)[v];
        int4 g = reinterpret_cast<const int4*>(mb)[v];
        float4 o;
        o.x = __expf(l.x - gmax[g.x]) * ginv[g.x];
        o.y = __expf(l.y - gmax[g.y]) * ginv[g.y];
        o.z = __expf(l.z - gmax[g.z]) * ginv[g.z];
        o.w = __expf(l.w - gmax[g.w]) * ginv[g.w];
        reinterpret_cast<float4*>(out)[v] = o;
    }
}

extern "C" void kernel_launch(void* const* d_in, const int* in_sizes, int n_in,
                              void* d_out, int out_size, void* d_ws, size_t ws_size,
                              hipStream_t stream) {
    const float* emb = (const float*)d_in[0];
    const int* moves = (const int*)d_in[1];
    const int* batch = (const int*)d_in[2];
    const float* W1 = (const float*)d_in[3];
    const float* b1 = (const float*)d_in[4];
    const float* W2 = (const float*)d_in[5];
    const float* b2 = (const float*)d_in[6];
    float* out = (float*)d_out;

    auto al = [](size_t x) { return (x + 255) & ~(size_t)255; };
    char* ws = (char*)d_ws;
    size_t off = 0;
    ushort* W1t = (ushort*)(ws + off); off += al((size_t)512 * 256 * 2);
    ushort* P   = (ushort*)(ws + off); off += al((size_t)NNODES * 512 * 2);
    float* logits = (float*)(ws + off); off += al((size_t)NMOVES * 4);
    int* mb       = (int*)(ws + off);   off += al((size_t)NMOVES * 4);
    float* pmax   = (float*)(ws + off); off += al((size_t)PB * NGRAPHS * 4);
    float* psum   = (float*)(ws + off); off += al((size_t)PB * NGRAPHS * 4);
    float* gmax   = (float*)(ws + off); off += al((size_t)NGRAPHS * 4);
    float* ginv   = (float*)(ws + off); off += al((size_t)NGRAPHS * 4);

    k_convert_w1<<<512, 256, 0, stream>>>(W1, W1t);

    int tiles_m = (NNODES + BM - 1) / BM;   // 782
    k_gemm<<<tiles_m, 512, 0, stream>>>(emb, W1t, P, NNODES);

    k_moves<<<2048, 256, 0, stream>>>(moves, moves + NMOVES, batch, P, b1, W2, b2,
                                      logits, mb);
    k_part<<<PB, 256, 0, stream>>>(logits, mb, pmax, psum);
    k_combine<<<NGRAPHS, 64, 0, stream>>>(pmax, psum, gmax, ginv);
    k_norm<<<512, 256, 0, stream>>>(logits, mb, gmax, ginv, out);
}